// Round 1
// 384.766 us; speedup vs baseline: 1.2049x; 1.2049x over previous
//
#include <hip/hip_runtime.h>

// B=4 T=4096 D=1024 H=16 HD=64 K=32 ; inputs f32, OUTPUTS f32.
// NO d_ws usage: all scratch lives inside the 67.1 MB f32 output-0 region.
#define B_ 4
#define T_ 4096
#define D_ 1024
#define H_ 16
#define K_ 32

// ---------------------------------------------------------------------------
// Scratch layout (f32 indices into outF; out0 = floats [0, 16777216)):
//   xs    [0      ,131072)   B*K x 1024   [atomic]
//   xbar  [131072 ,135168)   B x 1024     [atomic]
//   pad   [135168 ,196608)   zeros (rows 132..191 of gemm#1 A)
//   qkv   [196608 ,786432)   192 x 3072   [atomic]
//   u     [786432 ,917504)   128 x 1024   [pure write]
//   Mm    [917504 ,1048576)  128 x 1024   [atomic]  = out0 t-rows [896,1024)
//   pulse outF[16777216 +64), resp outF[16777280 +2048)
// k4_main writes every out0 row EXCEPT [896,1024) (M's home);
// k4_tailp (64 column-partitioned blocks) preloads its 32x16 slab of M[b=0]
// into LDS then overwrites rows [896,1024) at its own columns only —
// cross-block race-free because M reads are column-local.
// ---------------------------------------------------------------------------

__global__ __launch_bounds__(256) void k0_init(float4* __restrict__ a, int na,
                                               float4* __restrict__ b, int nb)
{
  int i = blockIdx.x * 256 + threadIdx.x;
  float4 z; z.x = 0.f; z.y = 0.f; z.z = 0.f; z.w = 0.f;
  if (i < na) a[i] = z;
  if (i < nb) b[i] = z;
}

// ---------------------------------------------------------------------------
// K1: xs[b][k][c] += sum_t sb[b,t,k]*x[b,t,c];  xbar[b][c] += sum_t x[b,t,c]
// grid (2, B, 32), block 256; thread owns 2 consecutive c; t-chunk = 128.
// ---------------------------------------------------------------------------
__global__ __launch_bounds__(256) void k1_spectral(
    const float* __restrict__ x, const float* __restrict__ sb,
    float* __restrict__ xs, float* __restrict__ xbar)
{
  const int b  = blockIdx.y;
  const int t0 = blockIdx.z * 128;
  const int c0 = blockIdx.x * 512 + threadIdx.x * 2;
  __shared__ float sbs[128][33];
  #pragma unroll
  for (int i = 0; i < 16; i++){
    int idx = threadIdx.x + i * 256;           // 4096 = 128t * 32k
    int k = idx & 31, t = idx >> 5;
    sbs[t][k] = sb[(size_t)(b * T_ + t0 + t) * K_ + k];
  }
  __syncthreads();
  float accx[32], accy[32];
  #pragma unroll
  for (int k = 0; k < 32; k++){ accx[k] = 0.f; accy[k] = 0.f; }
  float amx = 0.f, amy = 0.f;
  const float* xp = x + (size_t)(b * T_ + t0) * D_ + c0;
  for (int t = 0; t < 128; ++t){
    float2 xv = *(const float2*)(xp + (size_t)t * D_);
    amx += xv.x; amy += xv.y;
    #pragma unroll
    for (int k = 0; k < 32; k++){
      float s = sbs[t][k];
      accx[k] = fmaf(s, xv.x, accx[k]);
      accy[k] = fmaf(s, xv.y, accy[k]);
    }
  }
  float* xsp = xs + (size_t)b * K_ * D_ + c0;
  #pragma unroll
  for (int k = 0; k < 32; k++){
    atomicAdd(xsp + (size_t)k * D_,     accx[k]);
    atomicAdd(xsp + (size_t)k * D_ + 1, accy[k]);
  }
  atomicAdd(xbar + b * D_ + c0,     amx);
  atomicAdd(xbar + b * D_ + c0 + 1, amy);
}

// ---------------------------------------------------------------------------
// gemm_aw: C[m][n] += sum_c A[m][c]*W[n][c];  A f32 scratch, W f32 input
// grid (N/64, M/64, csplit), block 256; 64x64 tile; LDS staged transposed.
// ---------------------------------------------------------------------------
__global__ __launch_bounds__(256) void gemm_aw(
    const float* __restrict__ A, const float* __restrict__ W,
    float* __restrict__ C, const int N, const int cPerSplit)
{
  __shared__ __align__(16) float As[64][68];
  __shared__ __align__(16) float Ws[64][68];
  const int nt = blockIdx.x, mt = blockIdx.y;
  const int cbase = blockIdx.z * cPerSplit;
  const int tx = threadIdx.x & 15, ty = threadIdx.x >> 4;
  float acc[4][4];
  #pragma unroll
  for (int i = 0; i < 4; i++)
    #pragma unroll
    for (int j = 0; j < 4; j++) acc[i][j] = 0.f;

  for (int cc = 0; cc < cPerSplit; cc += 64){
    const int cb = cbase + cc;
    if (cc) __syncthreads();
    #pragma unroll
    for (int i = 0; i < 16; i++){
      int idx = threadIdx.x + i * 256;          // 4096 = 64m * 64c
      int c = idx & 63, m = idx >> 6;
      As[c][m] = A[(size_t)(mt * 64 + m) * 1024 + cb + c];
    }
    #pragma unroll
    for (int i = 0; i < 16; i++){
      int idx = threadIdx.x + i * 256;          // 4096 = 64n * 64c
      int c = idx & 63, n = idx >> 6;
      Ws[c][n] = W[(size_t)(nt * 64 + n) * 1024 + cb + c];
    }
    __syncthreads();
    #pragma unroll 4
    for (int c = 0; c < 64; ++c){
      const float4 a4 = *(const float4*)&As[c][ty * 4];
      const float4 w4 = *(const float4*)&Ws[c][tx * 4];
      acc[0][0] = fmaf(a4.x, w4.x, acc[0][0]);
      acc[0][1] = fmaf(a4.x, w4.y, acc[0][1]);
      acc[0][2] = fmaf(a4.x, w4.z, acc[0][2]);
      acc[0][3] = fmaf(a4.x, w4.w, acc[0][3]);
      acc[1][0] = fmaf(a4.y, w4.x, acc[1][0]);
      acc[1][1] = fmaf(a4.y, w4.y, acc[1][1]);
      acc[1][2] = fmaf(a4.y, w4.z, acc[1][2]);
      acc[1][3] = fmaf(a4.y, w4.w, acc[1][3]);
      acc[2][0] = fmaf(a4.z, w4.x, acc[2][0]);
      acc[2][1] = fmaf(a4.z, w4.y, acc[2][1]);
      acc[2][2] = fmaf(a4.z, w4.z, acc[2][2]);
      acc[2][3] = fmaf(a4.z, w4.w, acc[2][3]);
      acc[3][0] = fmaf(a4.w, w4.x, acc[3][0]);
      acc[3][1] = fmaf(a4.w, w4.y, acc[3][1]);
      acc[3][2] = fmaf(a4.w, w4.z, acc[3][2]);
      acc[3][3] = fmaf(a4.w, w4.w, acc[3][3]);
    }
  }
  #pragma unroll
  for (int i = 0; i < 4; i++){
    float* crow = C + (size_t)(mt * 64 + ty * 4 + i) * N + nt * 64 + tx * 4;
    #pragma unroll
    for (int j = 0; j < 4; j++) atomicAdd(crow + j, acc[i][j]);
  }
}

// ---------------------------------------------------------------------------
// K3: pulse (qkv row 128+b = xbar@Wqkv.T), attn_spec, soliton ODE, u=resp*v_spec
// grid 64 blocks (b*16+h), 64 threads. All outputs f32.
// ---------------------------------------------------------------------------
__global__ __launch_bounds__(64) void k3_small(
    const float* __restrict__ qkvC,
    const float* __restrict__ W1, const float* __restrict__ b1,
    const float* __restrict__ W2, const float* __restrict__ b2,
    const float* __restrict__ filt,
    const float* __restrict__ a_in, const float* __restrict__ b_in,
    float* __restrict__ u, float* __restrict__ out_pulse,
    float* __restrict__ out_resp)
{
  const int b = blockIdx.x >> 4, h = blockIdx.x & 15;
  const int d = threadIdx.x;
  __shared__ float qm[64];
  __shared__ float h1s[32];
  __shared__ float rsp[32];
  qm[d] = qkvC[(size_t)(128 + b) * 3072 + h * 64 + d] * (1.0f / 4096.0f);
  __syncthreads();
  if (d < 32){
    float z = b1[d];
    for (int j = 0; j < 64; j++) z = fmaf(qm[j], W1[d * 64 + j], z);
    h1s[d] = z / (1.0f + __expf(-z));             // silu
  }
  __syncthreads();
  if (d == 0){
    float z2 = b2[0];
    for (int j = 0; j < 32; j++) z2 = fmaf(h1s[j], W2[j], z2);
    out_pulse[b * H_ + h] = 4.0f + log1pf(__expf(z2));  // PULSE_BASE+softplus
  }
  if (d < 32){
    const int k = d;
    const float* qrow = qkvC + (size_t)(b * K_ + k) * 3072 + h * 64;
    const float* krow = qrow + 1024;
    float s = 0.f;
    for (int j = 0; j < 64; j++) s = fmaf(qrow[j], krow[j], s);
    float fg = 1.0f / (1.0f + __expf(-filt[h * 32 + k]));
    s = s * 0.125f * fg;                          // /sqrt(64)*sigmoid(filter)
    float av = a_in[0], bv = b_in[0];
    float sc = fmaxf(fabsf(s), 1e-6f);
    float sn = s / sc;
    float I  = (fabsf(s) > 0.5f) ? sn : 0.1f * sn;
    float v = 0.f, w = 0.f;
    #pragma unroll
    for (int it = 0; it < 5; ++it){
      float dv = v - v * v * v * (1.0f / 3.0f) - w + I;
      float dw = (v + av - bv * w) * 10.0f;       // /TAU
      v = fminf(fmaxf(v + 0.2f * dv, -3.0f), 3.0f);
      w = fminf(fmaxf(w + 0.2f * dw, -3.0f), 3.0f);
    }
    float r = v * sc;
    rsp[k] = r;
    out_resp[(b * H_ + h) * K_ + k] = r;
  }
  __syncthreads();
  for (int k = 0; k < 32; k++){
    u[(size_t)(b * K_ + k) * D_ + h * 64 + d] =
        rsp[k] * qkvC[(size_t)(b * K_ + k) * 3072 + 2048 + h * 64 + d];
  }
}

// ---------------------------------------------------------------------------
// k4_main: all out0 rows EXCEPT [896,1024) in a single launch.
// grid (2, 508), block 256; thread owns 2 consecutive e; 32 rows/chunk.
// yy<28 -> rows [0,896); yy>=28 -> rows [1024,16384). Never crosses b bound.
// ---------------------------------------------------------------------------
__global__ __launch_bounds__(256) void k4_main(
    const float* __restrict__ sb, const float* __restrict__ Mf,
    float* __restrict__ out)
{
  const int yy = blockIdx.y;
  const int r0 = (yy < 28 ? yy : yy + 4) * 32;   // skip M home rows [896,1024)
  const int b  = r0 >> 12;
  const int e0 = blockIdx.x * 512 + threadIdx.x * 2;
  __shared__ float sbs[32][33];
  #pragma unroll
  for (int i = 0; i < 4; i++){
    int idx = threadIdx.x + i * 256;           // 1024 = 32t * 32k
    int k = idx & 31, t = idx >> 5;
    sbs[t][k] = sb[(size_t)(r0 + t) * K_ + k];
  }
  __syncthreads();
  float mx[32], my[32];
  const float* mp = Mf + (size_t)b * K_ * D_ + e0;
  #pragma unroll
  for (int k = 0; k < 32; k++){ mx[k] = mp[(size_t)k * D_]; my[k] = mp[(size_t)k * D_ + 1]; }
  float* op = out + (size_t)r0 * D_ + e0;
  for (int t = 0; t < 32; ++t){
    float ox = 0.f, oy = 0.f;
    #pragma unroll
    for (int k = 0; k < 32; k++){
      float s = sbs[t][k];
      ox = fmaf(s, mx[k], ox);
      oy = fmaf(s, my[k], oy);
    }
    float2 o2; o2.x = ox; o2.y = oy;
    *(float2*)(op + (size_t)t * D_) = o2;
  }
}

// ---------------------------------------------------------------------------
// k4_tailp: out0 rows [896,1024) — M's home — COLUMN-PARTITIONED.
// grid (64), block 256. Block j owns columns [j*16, j*16+16).
// It reads only M[b=0][0:32][j*16 : j*16+16) (preloaded to LDS) and writes
// only rows [896,1024) at those columns -> no cross-block hazard; the
// intra-block read-before-write is ordered by __syncthreads().
// Thread: t = tid>>1 (row), c0 = (tid&1)*8 (col-octet); 8 outputs/thread.
// ---------------------------------------------------------------------------
__global__ __launch_bounds__(256) void k4_tailp(
    const float* __restrict__ sb, const float* __restrict__ Mf,
    float* __restrict__ out)
{
  __shared__ float sbs[128][33];               // 16.9 KB
  __shared__ __align__(16) float Ms[32][16];   // 2 KB: this block's M columns
  const int j = blockIdx.x;
  #pragma unroll
  for (int i = 0; i < 2; i++){
    int idx = threadIdx.x + i * 256;           // 512 = 32k * 16e
    int k = idx >> 4, e = idx & 15;
    Ms[k][e] = Mf[(size_t)k * D_ + j * 16 + e];
  }
  #pragma unroll
  for (int i = 0; i < 16; i++){
    int idx = threadIdx.x + i * 256;           // 4096 = 128t * 32k
    int k = idx & 31, t = idx >> 5;
    sbs[t][k] = sb[(size_t)(896 + t) * K_ + k];
  }
  __syncthreads();
  const int t  = threadIdx.x >> 1;
  const int c0 = (threadIdx.x & 1) * 8;
  float a0 = 0.f, a1 = 0.f, a2 = 0.f, a3 = 0.f;
  float a4 = 0.f, a5 = 0.f, a6 = 0.f, a7 = 0.f;
  #pragma unroll
  for (int k = 0; k < 32; k++){
    float s = sbs[t][k];
    const float4 m0 = *(const float4*)&Ms[k][c0];
    const float4 m1 = *(const float4*)&Ms[k][c0 + 4];
    a0 = fmaf(s, m0.x, a0); a1 = fmaf(s, m0.y, a1);
    a2 = fmaf(s, m0.z, a2); a3 = fmaf(s, m0.w, a3);
    a4 = fmaf(s, m1.x, a4); a5 = fmaf(s, m1.y, a5);
    a6 = fmaf(s, m1.z, a6); a7 = fmaf(s, m1.w, a7);
  }
  float* op = out + (size_t)(896 + t) * D_ + j * 16 + c0;
  float4 o0; o0.x = a0; o0.y = a1; o0.z = a2; o0.w = a3;
  float4 o1; o1.x = a4; o1.y = a5; o1.z = a6; o1.w = a7;
  *(float4*)(op)     = o0;
  *(float4*)(op + 4) = o1;
}

// ---------------------------------------------------------------------------
extern "C" void kernel_launch(void* const* d_in, const int* in_sizes, int n_in,
                              void* d_out, int out_size, void* d_ws, size_t ws_size,
                              hipStream_t stream)
{
  const float* x    = (const float*)d_in[0];
  const float* sb   = (const float*)d_in[1];
  const float* Wqkv = (const float*)d_in[2];
  const float* Wout = (const float*)d_in[3];
  const float* a_in = (const float*)d_in[4];
  const float* b_in = (const float*)d_in[5];
  const float* W1   = (const float*)d_in[6];
  const float* b1   = (const float*)d_in[7];
  const float* W2   = (const float*)d_in[8];
  const float* b2   = (const float*)d_in[9];
  const float* filt = (const float*)d_in[10];

  float* outF = (float*)d_out;
  float* xs   = outF;                 // see layout comment above
  float* xbar = outF + 131072;
  float* qkv  = outF + 196608;
  float* u    = outF + 786432;
  float* Mm   = outF + 917504;        // f32 M, out0 rows [896,1024)
  float* pulse = outF + 16777216;     // (B,H)   f32
  float* resp  = outF + 16777280;     // (B,H,K) f32

  k0_init<<<dim3(768), 256, 0, stream>>>((float4*)outF, 196608,
                                         (float4*)Mm, 32768);
  k1_spectral<<<dim3(2, 4, 32), 256, 0, stream>>>(x, sb, xs, xbar);
  // z-split 8 (was 4): 1152 blocks -> ~4.5/CU, hides staging latency
  gemm_aw<<<dim3(48, 3, 8), 256, 0, stream>>>(outF, Wqkv, qkv, 3072, 128);
  k3_small<<<dim3(64), dim3(64), 0, stream>>>(qkv, W1, b1, W2, b2,
                                              filt, a_in, b_in, u,
                                              pulse, resp);
  // z-split 16 (was 8): 512 blocks
  gemm_aw<<<dim3(16, 2, 16), 256, 0, stream>>>(u, Wout, Mm, 1024, 64);
  // All rows except M's home, single launch
  k4_main<<<dim3(2, 508), 256, 0, stream>>>(sb, Mm, outF);
  // M's home rows, column-partitioned across 64 blocks
  k4_tailp<<<dim3(64), 256, 0, stream>>>(sb, Mm, outF);
}

// Round 2
// 290.216 us; speedup vs baseline: 1.5975x; 1.3258x over previous
//
#include <hip/hip_runtime.h>

// B=4 T=4096 D=1024 H=16 HD=64 K=32 ; inputs f32, OUTPUTS f32.
// NO d_ws usage: all scratch lives inside the 67.1 MB f32 output-0 region.
// THIS REVISION: zero atomics anywhere. All split accumulations write
// disjoint per-z partial slabs, then reduce_z sums them.
#define B_ 4
#define T_ 4096
#define D_ 1024
#define H_ 16
#define K_ 32

// ---------------------------------------------------------------------------
// Scratch layout (f32 indices into outF; out0 = floats [0, 16777216)):
//   xs    [0      ,131072)   B*K x 1024   [store: reduce_z]
//   xbar  [131072 ,135168)   B x 1024     [store: reduce_z, contiguous w/ xs]
//   pad   [135168 ,196608)   zeros (rows 132..191 of gemm#1 A) [k0_init]
//   qkv   [196608 ,786432)   192 x 3072   [store: reduce_z]
//   u     [786432 ,917504)   128 x 1024   [pure write, k3]
//   Mm    [917504 ,1048576)  128 x 1024   [store: reduce_z] = out0 rows [896,1024)
//   S     [1048576,16777216) partial slabs, sequentially reused:
//     k1 partials  : 64 z-records of 135168 floats (xs_z ; xbar_z) = 8.65M
//     gemm1 partials: 8 x 589824 = 4.72M   (after reduce_xs done)
//     gemm2 partials: 32 x 131072 = 4.19M  (after reduce_qkv done)
//   pulse outF[16777216 +64), resp outF[16777280 +2048)
// All S consumers finish before k4_main overwrites rows [1024,16384).
// ---------------------------------------------------------------------------

__global__ __launch_bounds__(256) void k0_init(float4* __restrict__ a, int na)
{
  int i = blockIdx.x * 256 + threadIdx.x;
  float4 z; z.x = 0.f; z.y = 0.f; z.z = 0.f; z.w = 0.f;
  if (i < na) a[i] = z;
}

// ---------------------------------------------------------------------------
// reduce_z: dst[i] = sum_z src[z*stride4 + i]  (float4 lanes, pure BW)
// ---------------------------------------------------------------------------
__global__ __launch_bounds__(256) void reduce_z(
    const float4* __restrict__ src, float4* __restrict__ dst,
    const int n4, const int z, const int stride4)
{
  int i = blockIdx.x * 256 + threadIdx.x;
  if (i >= n4) return;
  float s0 = 0.f, s1 = 0.f, s2 = 0.f, s3 = 0.f;
  const float4* p = src + i;
  for (int zz = 0; zz < z; ++zz){
    float4 v = p[(size_t)zz * stride4];
    s0 += v.x; s1 += v.y; s2 += v.z; s3 += v.w;
  }
  float4 o; o.x = s0; o.y = s1; o.z = s2; o.w = s3;
  dst[i] = o;
}

// ---------------------------------------------------------------------------
// K1 (partials): XPz[b][k][c] = sum_{t in chunk z} sb[b,t,k]*x[b,t,c]
//                XPz[xbar][b][c] = sum_{t in chunk z} x[b,t,c]
// grid (2, B, 64), block 256; thread owns 2 consecutive c; t-chunk = 64.
// z-record = 135168 floats: [ xs_z (131072) ; xbar_z (4096) ].
// Pure stores; 2-deep register prefetch on the x stream.
// ---------------------------------------------------------------------------
__global__ __launch_bounds__(256) void k1_spectral_p(
    const float* __restrict__ x, const float* __restrict__ sb,
    float* __restrict__ XP)
{
  const int b  = blockIdx.y;
  const int zz = blockIdx.z;
  const int t0 = zz * 64;
  const int c0 = blockIdx.x * 512 + threadIdx.x * 2;
  __shared__ float sbs[64][33];
  #pragma unroll
  for (int i = 0; i < 8; i++){
    int idx = threadIdx.x + i * 256;           // 2048 = 64t * 32k
    int k = idx & 31, t = idx >> 5;
    sbs[t][k] = sb[(size_t)(b * T_ + t0 + t) * K_ + k];
  }
  __syncthreads();
  float accx[32], accy[32];
  #pragma unroll
  for (int k = 0; k < 32; k++){ accx[k] = 0.f; accy[k] = 0.f; }
  float amx = 0.f, amy = 0.f;
  const float* xp = x + (size_t)(b * T_ + t0) * D_ + c0;
  float2 p0 = *(const float2*)xp;
  float2 p1 = *(const float2*)(xp + D_);
  for (int t = 0; t < 64; ++t){
    float2 xv = p0;
    p0 = p1;
    if (t < 62) p1 = *(const float2*)(xp + (size_t)(t + 2) * D_);
    amx += xv.x; amy += xv.y;
    #pragma unroll
    for (int k = 0; k < 32; k++){
      float s = sbs[t][k];
      accx[k] = fmaf(s, xv.x, accx[k]);
      accy[k] = fmaf(s, xv.y, accy[k]);
    }
  }
  float* o = XP + (size_t)zz * 135168 + (size_t)(b * K_) * D_ + c0;
  #pragma unroll
  for (int k = 0; k < 32; k++){
    float2 w; w.x = accx[k]; w.y = accy[k];
    *(float2*)(o + (size_t)k * D_) = w;
  }
  float2 wb; wb.x = amx; wb.y = amy;
  *(float2*)(XP + (size_t)zz * 135168 + 131072 + b * D_ + c0) = wb;
}

// ---------------------------------------------------------------------------
// gemm_aw_p: Cp[z][m][n] = sum_{c in split} A[m][c]*W[n][c]; PURE STORES.
// grid (N/64, M/64, csplit), block 256; 64x64 tile; c-chunk 32 (17.4 KB LDS
// -> ~7 blocks/CU resident).
// ---------------------------------------------------------------------------
__global__ __launch_bounds__(256) void gemm_aw_p(
    const float* __restrict__ A, const float* __restrict__ W,
    float* __restrict__ Cp, const int N, const int cPerSplit, const int MN)
{
  __shared__ __align__(16) float As[32][68];
  __shared__ __align__(16) float Ws[32][68];
  const int nt = blockIdx.x, mt = blockIdx.y;
  const int cbase = blockIdx.z * cPerSplit;
  const int tx = threadIdx.x & 15, ty = threadIdx.x >> 4;
  float acc[4][4];
  #pragma unroll
  for (int i = 0; i < 4; i++)
    #pragma unroll
    for (int j = 0; j < 4; j++) acc[i][j] = 0.f;

  for (int cc = 0; cc < cPerSplit; cc += 32){
    const int cb = cbase + cc;
    if (cc) __syncthreads();
    #pragma unroll
    for (int i = 0; i < 8; i++){
      int idx = threadIdx.x + i * 256;          // 2048 = 64m * 32c
      int c = idx & 31, m = idx >> 5;
      As[c][m] = A[(size_t)(mt * 64 + m) * 1024 + cb + c];
    }
    #pragma unroll
    for (int i = 0; i < 8; i++){
      int idx = threadIdx.x + i * 256;          // 2048 = 64n * 32c
      int c = idx & 31, n = idx >> 5;
      Ws[c][n] = W[(size_t)(nt * 64 + n) * 1024 + cb + c];
    }
    __syncthreads();
    #pragma unroll 4
    for (int c = 0; c < 32; ++c){
      const float4 a4 = *(const float4*)&As[c][ty * 4];
      const float4 w4 = *(const float4*)&Ws[c][tx * 4];
      acc[0][0] = fmaf(a4.x, w4.x, acc[0][0]);
      acc[0][1] = fmaf(a4.x, w4.y, acc[0][1]);
      acc[0][2] = fmaf(a4.x, w4.z, acc[0][2]);
      acc[0][3] = fmaf(a4.x, w4.w, acc[0][3]);
      acc[1][0] = fmaf(a4.y, w4.x, acc[1][0]);
      acc[1][1] = fmaf(a4.y, w4.y, acc[1][1]);
      acc[1][2] = fmaf(a4.y, w4.z, acc[1][2]);
      acc[1][3] = fmaf(a4.y, w4.w, acc[1][3]);
      acc[2][0] = fmaf(a4.z, w4.x, acc[2][0]);
      acc[2][1] = fmaf(a4.z, w4.y, acc[2][1]);
      acc[2][2] = fmaf(a4.z, w4.z, acc[2][2]);
      acc[2][3] = fmaf(a4.z, w4.w, acc[2][3]);
      acc[3][0] = fmaf(a4.w, w4.x, acc[3][0]);
      acc[3][1] = fmaf(a4.w, w4.y, acc[3][1]);
      acc[3][2] = fmaf(a4.w, w4.z, acc[3][2]);
      acc[3][3] = fmaf(a4.w, w4.w, acc[3][3]);
    }
  }
  float* cp = Cp + (size_t)blockIdx.z * MN;
  #pragma unroll
  for (int i = 0; i < 4; i++){
    float4 o; o.x = acc[i][0]; o.y = acc[i][1]; o.z = acc[i][2]; o.w = acc[i][3];
    *(float4*)(cp + (size_t)(mt * 64 + ty * 4 + i) * N + nt * 64 + tx * 4) = o;
  }
}

// ---------------------------------------------------------------------------
// K3: pulse (qkv row 128+b = xbar@Wqkv.T), attn_spec, soliton ODE, u=resp*v_spec
// grid 64 blocks (b*16+h), 64 threads. All outputs f32.
// ---------------------------------------------------------------------------
__global__ __launch_bounds__(64) void k3_small(
    const float* __restrict__ qkvC,
    const float* __restrict__ W1, const float* __restrict__ b1,
    const float* __restrict__ W2, const float* __restrict__ b2,
    const float* __restrict__ filt,
    const float* __restrict__ a_in, const float* __restrict__ b_in,
    float* __restrict__ u, float* __restrict__ out_pulse,
    float* __restrict__ out_resp)
{
  const int b = blockIdx.x >> 4, h = blockIdx.x & 15;
  const int d = threadIdx.x;
  __shared__ float qm[64];
  __shared__ float h1s[32];
  __shared__ float rsp[32];
  qm[d] = qkvC[(size_t)(128 + b) * 3072 + h * 64 + d] * (1.0f / 4096.0f);
  __syncthreads();
  if (d < 32){
    float z = b1[d];
    for (int j = 0; j < 64; j++) z = fmaf(qm[j], W1[d * 64 + j], z);
    h1s[d] = z / (1.0f + __expf(-z));             // silu
  }
  __syncthreads();
  if (d == 0){
    float z2 = b2[0];
    for (int j = 0; j < 32; j++) z2 = fmaf(h1s[j], W2[j], z2);
    out_pulse[b * H_ + h] = 4.0f + log1pf(__expf(z2));  // PULSE_BASE+softplus
  }
  if (d < 32){
    const int k = d;
    const float* qrow = qkvC + (size_t)(b * K_ + k) * 3072 + h * 64;
    const float* krow = qrow + 1024;
    float s = 0.f;
    for (int j = 0; j < 64; j++) s = fmaf(qrow[j], krow[j], s);
    float fg = 1.0f / (1.0f + __expf(-filt[h * 32 + k]));
    s = s * 0.125f * fg;                          // /sqrt(64)*sigmoid(filter)
    float av = a_in[0], bv = b_in[0];
    float sc = fmaxf(fabsf(s), 1e-6f);
    float sn = s / sc;
    float I  = (fabsf(s) > 0.5f) ? sn : 0.1f * sn;
    float v = 0.f, w = 0.f;
    #pragma unroll
    for (int it = 0; it < 5; ++it){
      float dv = v - v * v * v * (1.0f / 3.0f) - w + I;
      float dw = (v + av - bv * w) * 10.0f;       // /TAU
      v = fminf(fmaxf(v + 0.2f * dv, -3.0f), 3.0f);
      w = fminf(fmaxf(w + 0.2f * dw, -3.0f), 3.0f);
    }
    float r = v * sc;
    rsp[k] = r;
    out_resp[(b * H_ + h) * K_ + k] = r;
  }
  __syncthreads();
  for (int k = 0; k < 32; k++){
    u[(size_t)(b * K_ + k) * D_ + h * 64 + d] =
        rsp[k] * qkvC[(size_t)(b * K_ + k) * 3072 + 2048 + h * 64 + d];
  }
}

// ---------------------------------------------------------------------------
// k4_main: all out0 rows EXCEPT [896,1024) in a single launch.
// grid (2, 508), block 256; thread owns 2 consecutive e; 32 rows/chunk.
// ---------------------------------------------------------------------------
__global__ __launch_bounds__(256) void k4_main(
    const float* __restrict__ sb, const float* __restrict__ Mf,
    float* __restrict__ out)
{
  const int yy = blockIdx.y;
  const int r0 = (yy < 28 ? yy : yy + 4) * 32;   // skip M home rows [896,1024)
  const int b  = r0 >> 12;
  const int e0 = blockIdx.x * 512 + threadIdx.x * 2;
  __shared__ float sbs[32][33];
  #pragma unroll
  for (int i = 0; i < 4; i++){
    int idx = threadIdx.x + i * 256;           // 1024 = 32t * 32k
    int k = idx & 31, t = idx >> 5;
    sbs[t][k] = sb[(size_t)(r0 + t) * K_ + k];
  }
  __syncthreads();
  float mx[32], my[32];
  const float* mp = Mf + (size_t)b * K_ * D_ + e0;
  #pragma unroll
  for (int k = 0; k < 32; k++){ mx[k] = mp[(size_t)k * D_]; my[k] = mp[(size_t)k * D_ + 1]; }
  float* op = out + (size_t)r0 * D_ + e0;
  for (int t = 0; t < 32; ++t){
    float ox = 0.f, oy = 0.f;
    #pragma unroll
    for (int k = 0; k < 32; k++){
      float s = sbs[t][k];
      ox = fmaf(s, mx[k], ox);
      oy = fmaf(s, my[k], oy);
    }
    float2 o2; o2.x = ox; o2.y = oy;
    *(float2*)(op + (size_t)t * D_) = o2;
  }
}

// ---------------------------------------------------------------------------
// k4_tailp: out0 rows [896,1024) — M's home — COLUMN-PARTITIONED.
// grid (64), block 256. Block j owns columns [j*16, j*16+16); race-free.
// ---------------------------------------------------------------------------
__global__ __launch_bounds__(256) void k4_tailp(
    const float* __restrict__ sb, const float* __restrict__ Mf,
    float* __restrict__ out)
{
  __shared__ float sbs[128][33];               // 16.9 KB
  __shared__ __align__(16) float Ms[32][16];   // 2 KB: this block's M columns
  const int j = blockIdx.x;
  #pragma unroll
  for (int i = 0; i < 2; i++){
    int idx = threadIdx.x + i * 256;           // 512 = 32k * 16e
    int k = idx >> 4, e = idx & 15;
    Ms[k][e] = Mf[(size_t)k * D_ + j * 16 + e];
  }
  #pragma unroll
  for (int i = 0; i < 16; i++){
    int idx = threadIdx.x + i * 256;           // 4096 = 128t * 32k
    int k = idx & 31, t = idx >> 5;
    sbs[t][k] = sb[(size_t)(896 + t) * K_ + k];
  }
  __syncthreads();
  const int t  = threadIdx.x >> 1;
  const int c0 = (threadIdx.x & 1) * 8;
  float a0 = 0.f, a1 = 0.f, a2 = 0.f, a3 = 0.f;
  float a4 = 0.f, a5 = 0.f, a6 = 0.f, a7 = 0.f;
  #pragma unroll
  for (int k = 0; k < 32; k++){
    float s = sbs[t][k];
    const float4 m0 = *(const float4*)&Ms[k][c0];
    const float4 m1 = *(const float4*)&Ms[k][c0 + 4];
    a0 = fmaf(s, m0.x, a0); a1 = fmaf(s, m0.y, a1);
    a2 = fmaf(s, m0.z, a2); a3 = fmaf(s, m0.w, a3);
    a4 = fmaf(s, m1.x, a4); a5 = fmaf(s, m1.y, a5);
    a6 = fmaf(s, m1.z, a6); a7 = fmaf(s, m1.w, a7);
  }
  float* op = out + (size_t)(896 + t) * D_ + j * 16 + c0;
  float4 o0; o0.x = a0; o0.y = a1; o0.z = a2; o0.w = a3;
  float4 o1; o1.x = a4; o1.y = a5; o1.z = a6; o1.w = a7;
  *(float4*)(op)     = o0;
  *(float4*)(op + 4) = o1;
}

// ---------------------------------------------------------------------------
extern "C" void kernel_launch(void* const* d_in, const int* in_sizes, int n_in,
                              void* d_out, int out_size, void* d_ws, size_t ws_size,
                              hipStream_t stream)
{
  const float* x    = (const float*)d_in[0];
  const float* sb   = (const float*)d_in[1];
  const float* Wqkv = (const float*)d_in[2];
  const float* Wout = (const float*)d_in[3];
  const float* a_in = (const float*)d_in[4];
  const float* b_in = (const float*)d_in[5];
  const float* W1   = (const float*)d_in[6];
  const float* b1   = (const float*)d_in[7];
  const float* W2   = (const float*)d_in[8];
  const float* b2   = (const float*)d_in[9];
  const float* filt = (const float*)d_in[10];

  float* outF = (float*)d_out;
  float* qkv  = outF + 196608;
  float* u    = outF + 786432;
  float* Mm   = outF + 917504;        // f32 M, out0 rows [896,1024)
  float* S    = outF + 1048576;       // partial slabs (sequentially reused)
  float* pulse = outF + 16777216;     // (B,H)   f32
  float* resp  = outF + 16777280;     // (B,H,K) f32

  // zero only the pad rows 132..191 of gemm#1's A (floats [135168,196608))
  k0_init<<<dim3(60), 256, 0, stream>>>((float4*)(outF + 135168), 15360);

  // spectral projection partials (z = 64 t-chunks), then reduce into xs+xbar
  k1_spectral_p<<<dim3(2, 4, 64), 256, 0, stream>>>(x, sb, S);
  reduce_z<<<dim3(132), 256, 0, stream>>>((const float4*)S, (float4*)outF,
                                          33792, 64, 33792);

  // qkv GEMM: 8-way split-K partials -> reduce
  gemm_aw_p<<<dim3(48, 3, 8), 256, 0, stream>>>(outF, Wqkv, S, 3072, 128, 589824);
  reduce_z<<<dim3(576), 256, 0, stream>>>((const float4*)S, (float4*)qkv,
                                          147456, 8, 147456);

  k3_small<<<dim3(64), dim3(64), 0, stream>>>(qkv, W1, b1, W2, b2,
                                              filt, a_in, b_in, u,
                                              pulse, resp);

  // out GEMM: 32-way split-K partials -> reduce into Mm
  gemm_aw_p<<<dim3(16, 2, 32), 256, 0, stream>>>(u, Wout, S, 1024, 32, 131072);
  reduce_z<<<dim3(128), 256, 0, stream>>>((const float4*)S, (float4*)Mm,
                                          32768, 32, 32768);

  // All rows except M's home, single launch
  k4_main<<<dim3(2, 508), 256, 0, stream>>>(sb, Mm, outF);
  // M's home rows, column-partitioned across 64 blocks
  k4_tailp<<<dim3(64), 256, 0, stream>>>(sb, Mm, outF);
}

// Round 3
// 283.439 us; speedup vs baseline: 1.6357x; 1.0239x over previous
//
#include <hip/hip_runtime.h>

// B=4 T=4096 D=1024 H=16 HD=64 K=32 ; inputs f32, OUTPUTS f32.
// NO d_ws usage: all scratch lives inside the 67.1 MB f32 output-0 region.
// Zero atomics: split accumulations write disjoint per-z partial slabs,
// then reduce_z sums them.
#define B_ 4
#define T_ 4096
#define D_ 1024
#define H_ 16
#define K_ 32

// ---------------------------------------------------------------------------
// Scratch layout (f32 indices into outF; out0 = floats [0, 16777216)):
//   xs    [0      ,131072)   B*K x 1024   [reduce_z dst]
//   xbar  [131072 ,135168)   B x 1024     [reduce_z dst, contiguous w/ xs]
//   pad   [135168 ,196608)   zeros (rows 132..191 of gemm#1 A) [k0_init]
//   qkv   [196608 ,786432)   192 x 3072   [reduce_z dst]
//   u     [786432 ,917504)   128 x 1024   [pure write, k3]
//   Mm    [917504 ,1048576)  128 x 1024   [reduce_z dst] = out0 rows [896,1024)
//   S     [1048576,16777216) partial slabs, sequentially reused:
//     k1 partials  : 64 z-records of 135168 floats = 8.65M   (ends 9.70M)
//     gemm1 partials: 16 x 589824 = 9.44M  (after reduce_xs consumed k1's)
//     gemm2 partials: 32 x 131072 = 4.19M  (after reduce_qkv consumed gemm1's)
//   pulse outF[16777216 +64), resp outF[16777280 +2048)
// All S consumers finish before k4_main overwrites rows [1024,16384).
// ---------------------------------------------------------------------------

__global__ __launch_bounds__(256) void k0_init(float4* __restrict__ a, int na)
{
  int i = blockIdx.x * 256 + threadIdx.x;
  float4 z; z.x = 0.f; z.y = 0.f; z.z = 0.f; z.w = 0.f;
  if (i < na) a[i] = z;
}

// ---------------------------------------------------------------------------
// reduce_z: dst[i] = sum_z src[z*stride4 + i]  (float4 lanes, pure BW)
// ---------------------------------------------------------------------------
__global__ __launch_bounds__(256) void reduce_z(
    const float4* __restrict__ src, float4* __restrict__ dst,
    const int n4, const int z, const int stride4)
{
  int i = blockIdx.x * 256 + threadIdx.x;
  if (i >= n4) return;
  float s0 = 0.f, s1 = 0.f, s2 = 0.f, s3 = 0.f;
  const float4* p = src + i;
  for (int zz = 0; zz < z; ++zz){
    float4 v = p[(size_t)zz * stride4];
    s0 += v.x; s1 += v.y; s2 += v.z; s3 += v.w;
  }
  float4 o; o.x = s0; o.y = s1; o.z = s2; o.w = s3;
  dst[i] = o;
}

// ---------------------------------------------------------------------------
// K1 (partials): XPz[b][k][c] = sum_{t in chunk z} sb[b,t,k]*x[b,t,c]
//                XPz[xbar][b][c] = sum_{t in chunk z} x[b,t,c]
// grid (4, B, 64), block 256; ONE c per thread (4B/lane, 256B/wave,
// contiguous); t-chunk = 64; 4-deep register prefetch on the x stream.
// 1024 blocks -> 4/CU -> 16 waves/CU; latency tolerance ~= 4 deep x 64 cyc.
// z-record = 135168 floats: [ xs_z (131072) ; xbar_z (4096) ].
// ---------------------------------------------------------------------------
__global__ __launch_bounds__(256) void k1_spectral_p(
    const float* __restrict__ x, const float* __restrict__ sb,
    float* __restrict__ XP)
{
  const int b  = blockIdx.y;
  const int zz = blockIdx.z;
  const int t0 = zz * 64;
  const int c  = blockIdx.x * 256 + threadIdx.x;
  __shared__ float sbs[64][33];
  #pragma unroll
  for (int i = 0; i < 8; i++){
    int idx = threadIdx.x + i * 256;           // 2048 = 64t * 32k
    int k = idx & 31, t = idx >> 5;
    sbs[t][k] = sb[(size_t)(b * T_ + t0 + t) * K_ + k];
  }
  __syncthreads();
  float acc[32];
  #pragma unroll
  for (int k = 0; k < 32; k++) acc[k] = 0.f;
  float am = 0.f;
  const float* xp = x + (size_t)(b * T_ + t0) * D_ + c;
  float p0 = xp[0];
  float p1 = xp[D_];
  float p2 = xp[2 * D_];
  float p3 = xp[3 * D_];
  #pragma unroll 4
  for (int t = 0; t < 64; ++t){
    float xv = p0; p0 = p1; p1 = p2; p2 = p3;
    if (t < 60) p3 = xp[(size_t)(t + 4) * D_];
    am += xv;
    #pragma unroll
    for (int k = 0; k < 32; k++) acc[k] = fmaf(sbs[t][k], xv, acc[k]);
  }
  float* o = XP + (size_t)zz * 135168 + (size_t)(b * K_) * D_ + c;
  #pragma unroll
  for (int k = 0; k < 32; k++) o[(size_t)k * D_] = acc[k];
  XP[(size_t)zz * 135168 + 131072 + b * D_ + c] = am;
}

// ---------------------------------------------------------------------------
// gemm_aw_p: Cp[z][m][n] = sum_{c in split} A[m][c]*W[n][c]; PURE STORES.
// grid (N/64, M/64, csplit), block 256; 64x64 tile; c-chunk 32 (17.4 KB LDS).
// Register-staged double buffer: next chunk's global loads issue BEFORE the
// current chunk's compute; vmcnt drains only at the post-barrier ds_write.
// ---------------------------------------------------------------------------
__global__ __launch_bounds__(256) void gemm_aw_p(
    const float* __restrict__ A, const float* __restrict__ W,
    float* __restrict__ Cp, const int N, const int cPerSplit, const int MN)
{
  __shared__ __align__(16) float As[32][68];
  __shared__ __align__(16) float Ws[32][68];
  const int nt = blockIdx.x, mt = blockIdx.y;
  const int cbase = blockIdx.z * cPerSplit;
  const int tx = threadIdx.x & 15, ty = threadIdx.x >> 4;
  const int sc = threadIdx.x & 31, sr = threadIdx.x >> 5;  // staging coords
  float acc[4][4];
  #pragma unroll
  for (int i = 0; i < 4; i++)
    #pragma unroll
    for (int j = 0; j < 4; j++) acc[i][j] = 0.f;

  float ra[8], rw[8];
  const float* Ap = A + (size_t)(mt * 64 + sr) * 1024 + cbase + sc;
  const float* Wp = W + (size_t)(nt * 64 + sr) * 1024 + cbase + sc;
  // prologue: load chunk 0 into regs, stage to LDS
  #pragma unroll
  for (int i = 0; i < 8; i++){ ra[i] = Ap[(size_t)(i * 8) * 1024];
                               rw[i] = Wp[(size_t)(i * 8) * 1024]; }
  #pragma unroll
  for (int i = 0; i < 8; i++){ As[sc][sr + i * 8] = ra[i];
                               Ws[sc][sr + i * 8] = rw[i]; }
  __syncthreads();

  for (int cc = 32; cc < cPerSplit; cc += 32){
    // issue next chunk's loads (overlap with compute below)
    #pragma unroll
    for (int i = 0; i < 8; i++){ ra[i] = Ap[(size_t)(i * 8) * 1024 + cc];
                                 rw[i] = Wp[(size_t)(i * 8) * 1024 + cc]; }
    #pragma unroll 4
    for (int c = 0; c < 32; ++c){
      const float4 a4 = *(const float4*)&As[c][ty * 4];
      const float4 w4 = *(const float4*)&Ws[c][tx * 4];
      acc[0][0] = fmaf(a4.x, w4.x, acc[0][0]);
      acc[0][1] = fmaf(a4.x, w4.y, acc[0][1]);
      acc[0][2] = fmaf(a4.x, w4.z, acc[0][2]);
      acc[0][3] = fmaf(a4.x, w4.w, acc[0][3]);
      acc[1][0] = fmaf(a4.y, w4.x, acc[1][0]);
      acc[1][1] = fmaf(a4.y, w4.y, acc[1][1]);
      acc[1][2] = fmaf(a4.y, w4.z, acc[1][2]);
      acc[1][3] = fmaf(a4.y, w4.w, acc[1][3]);
      acc[2][0] = fmaf(a4.z, w4.x, acc[2][0]);
      acc[2][1] = fmaf(a4.z, w4.y, acc[2][1]);
      acc[2][2] = fmaf(a4.z, w4.z, acc[2][2]);
      acc[2][3] = fmaf(a4.z, w4.w, acc[2][3]);
      acc[3][0] = fmaf(a4.w, w4.x, acc[3][0]);
      acc[3][1] = fmaf(a4.w, w4.y, acc[3][1]);
      acc[3][2] = fmaf(a4.w, w4.z, acc[3][2]);
      acc[3][3] = fmaf(a4.w, w4.w, acc[3][3]);
    }
    __syncthreads();
    #pragma unroll
    for (int i = 0; i < 8; i++){ As[sc][sr + i * 8] = ra[i];
                                 Ws[sc][sr + i * 8] = rw[i]; }
    __syncthreads();
  }
  // final chunk compute
  #pragma unroll 4
  for (int c = 0; c < 32; ++c){
    const float4 a4 = *(const float4*)&As[c][ty * 4];
    const float4 w4 = *(const float4*)&Ws[c][tx * 4];
    acc[0][0] = fmaf(a4.x, w4.x, acc[0][0]);
    acc[0][1] = fmaf(a4.x, w4.y, acc[0][1]);
    acc[0][2] = fmaf(a4.x, w4.z, acc[0][2]);
    acc[0][3] = fmaf(a4.x, w4.w, acc[0][3]);
    acc[1][0] = fmaf(a4.y, w4.x, acc[1][0]);
    acc[1][1] = fmaf(a4.y, w4.y, acc[1][1]);
    acc[1][2] = fmaf(a4.y, w4.z, acc[1][2]);
    acc[1][3] = fmaf(a4.y, w4.w, acc[1][3]);
    acc[2][0] = fmaf(a4.z, w4.x, acc[2][0]);
    acc[2][1] = fmaf(a4.z, w4.y, acc[2][1]);
    acc[2][2] = fmaf(a4.z, w4.z, acc[2][2]);
    acc[2][3] = fmaf(a4.z, w4.w, acc[2][3]);
    acc[3][0] = fmaf(a4.w, w4.x, acc[3][0]);
    acc[3][1] = fmaf(a4.w, w4.y, acc[3][1]);
    acc[3][2] = fmaf(a4.w, w4.z, acc[3][2]);
    acc[3][3] = fmaf(a4.w, w4.w, acc[3][3]);
  }
  float* cp = Cp + (size_t)blockIdx.z * MN;
  #pragma unroll
  for (int i = 0; i < 4; i++){
    float4 o; o.x = acc[i][0]; o.y = acc[i][1]; o.z = acc[i][2]; o.w = acc[i][3];
    *(float4*)(cp + (size_t)(mt * 64 + ty * 4 + i) * N + nt * 64 + tx * 4) = o;
  }
}

// ---------------------------------------------------------------------------
// K3: pulse (qkv row 128+b = xbar@Wqkv.T), attn_spec, soliton ODE, u=resp*v_spec
// grid 64 blocks (b*16+h), 64 threads. All outputs f32.
// ---------------------------------------------------------------------------
__global__ __launch_bounds__(64) void k3_small(
    const float* __restrict__ qkvC,
    const float* __restrict__ W1, const float* __restrict__ b1,
    const float* __restrict__ W2, const float* __restrict__ b2,
    const float* __restrict__ filt,
    const float* __restrict__ a_in, const float* __restrict__ b_in,
    float* __restrict__ u, float* __restrict__ out_pulse,
    float* __restrict__ out_resp)
{
  const int b = blockIdx.x >> 4, h = blockIdx.x & 15;
  const int d = threadIdx.x;
  __shared__ float qm[64];
  __shared__ float h1s[32];
  __shared__ float rsp[32];
  qm[d] = qkvC[(size_t)(128 + b) * 3072 + h * 64 + d] * (1.0f / 4096.0f);
  __syncthreads();
  if (d < 32){
    float z = b1[d];
    for (int j = 0; j < 64; j++) z = fmaf(qm[j], W1[d * 64 + j], z);
    h1s[d] = z / (1.0f + __expf(-z));             // silu
  }
  __syncthreads();
  if (d == 0){
    float z2 = b2[0];
    for (int j = 0; j < 32; j++) z2 = fmaf(h1s[j], W2[j], z2);
    out_pulse[b * H_ + h] = 4.0f + log1pf(__expf(z2));  // PULSE_BASE+softplus
  }
  if (d < 32){
    const int k = d;
    const float* qrow = qkvC + (size_t)(b * K_ + k) * 3072 + h * 64;
    const float* krow = qrow + 1024;
    float s = 0.f;
    for (int j = 0; j < 64; j++) s = fmaf(qrow[j], krow[j], s);
    float fg = 1.0f / (1.0f + __expf(-filt[h * 32 + k]));
    s = s * 0.125f * fg;                          // /sqrt(64)*sigmoid(filter)
    float av = a_in[0], bv = b_in[0];
    float sc = fmaxf(fabsf(s), 1e-6f);
    float sn = s / sc;
    float I  = (fabsf(s) > 0.5f) ? sn : 0.1f * sn;
    float v = 0.f, w = 0.f;
    #pragma unroll
    for (int it = 0; it < 5; ++it){
      float dv = v - v * v * v * (1.0f / 3.0f) - w + I;
      float dw = (v + av - bv * w) * 10.0f;       // /TAU
      v = fminf(fmaxf(v + 0.2f * dv, -3.0f), 3.0f);
      w = fminf(fmaxf(w + 0.2f * dw, -3.0f), 3.0f);
    }
    float r = v * sc;
    rsp[k] = r;
    out_resp[(b * H_ + h) * K_ + k] = r;
  }
  __syncthreads();
  for (int k = 0; k < 32; k++){
    u[(size_t)(b * K_ + k) * D_ + h * 64 + d] =
        rsp[k] * qkvC[(size_t)(b * K_ + k) * 3072 + 2048 + h * 64 + d];
  }
}

// ---------------------------------------------------------------------------
// k4_main: all out0 rows EXCEPT [896,1024); 16-row chunks for 2x TLP.
// grid (2, 1016), block 256; thread owns 2 consecutive e.
// yy<56 -> rows [0,896); yy>=56 -> rows [1024,16384). Never crosses b bound.
// ---------------------------------------------------------------------------
__global__ __launch_bounds__(256) void k4_main(
    const float* __restrict__ sb, const float* __restrict__ Mf,
    float* __restrict__ out)
{
  const int yy = blockIdx.y;
  const int r0 = (yy < 56 ? yy : yy + 8) * 16;   // skip M home rows [896,1024)
  const int b  = r0 >> 12;
  const int e0 = blockIdx.x * 512 + threadIdx.x * 2;
  __shared__ float sbs[16][33];
  #pragma unroll
  for (int i = 0; i < 2; i++){
    int idx = threadIdx.x + i * 256;           // 512 = 16t * 32k
    int k = idx & 31, t = idx >> 5;
    sbs[t][k] = sb[(size_t)(r0 + t) * K_ + k];
  }
  __syncthreads();
  float mx[32], my[32];
  const float* mp = Mf + (size_t)b * K_ * D_ + e0;
  #pragma unroll
  for (int k = 0; k < 32; k++){ mx[k] = mp[(size_t)k * D_]; my[k] = mp[(size_t)k * D_ + 1]; }
  float* op = out + (size_t)r0 * D_ + e0;
  for (int t = 0; t < 16; ++t){
    float ox = 0.f, oy = 0.f;
    #pragma unroll
    for (int k = 0; k < 32; k++){
      float s = sbs[t][k];
      ox = fmaf(s, mx[k], ox);
      oy = fmaf(s, my[k], oy);
    }
    float2 o2; o2.x = ox; o2.y = oy;
    *(float2*)(op + (size_t)t * D_) = o2;
  }
}

// ---------------------------------------------------------------------------
// k4_tailp: out0 rows [896,1024) — M's home — COLUMN-PARTITIONED.
// grid (64), block 256. Block j owns columns [j*16, j*16+16); race-free.
// ---------------------------------------------------------------------------
__global__ __launch_bounds__(256) void k4_tailp(
    const float* __restrict__ sb, const float* __restrict__ Mf,
    float* __restrict__ out)
{
  __shared__ float sbs[128][33];               // 16.9 KB
  __shared__ __align__(16) float Ms[32][16];   // 2 KB: this block's M columns
  const int j = blockIdx.x;
  #pragma unroll
  for (int i = 0; i < 2; i++){
    int idx = threadIdx.x + i * 256;           // 512 = 32k * 16e
    int k = idx >> 4, e = idx & 15;
    Ms[k][e] = Mf[(size_t)k * D_ + j * 16 + e];
  }
  #pragma unroll
  for (int i = 0; i < 16; i++){
    int idx = threadIdx.x + i * 256;           // 4096 = 128t * 32k
    int k = idx & 31, t = idx >> 5;
    sbs[t][k] = sb[(size_t)(896 + t) * K_ + k];
  }
  __syncthreads();
  const int t  = threadIdx.x >> 1;
  const int c0 = (threadIdx.x & 1) * 8;
  float a0 = 0.f, a1 = 0.f, a2 = 0.f, a3 = 0.f;
  float a4 = 0.f, a5 = 0.f, a6 = 0.f, a7 = 0.f;
  #pragma unroll
  for (int k = 0; k < 32; k++){
    float s = sbs[t][k];
    const float4 m0 = *(const float4*)&Ms[k][c0];
    const float4 m1 = *(const float4*)&Ms[k][c0 + 4];
    a0 = fmaf(s, m0.x, a0); a1 = fmaf(s, m0.y, a1);
    a2 = fmaf(s, m0.z, a2); a3 = fmaf(s, m0.w, a3);
    a4 = fmaf(s, m1.x, a4); a5 = fmaf(s, m1.y, a5);
    a6 = fmaf(s, m1.z, a6); a7 = fmaf(s, m1.w, a7);
  }
  float* op = out + (size_t)(896 + t) * D_ + j * 16 + c0;
  float4 o0; o0.x = a0; o0.y = a1; o0.z = a2; o0.w = a3;
  float4 o1; o1.x = a4; o1.y = a5; o1.z = a6; o1.w = a7;
  *(float4*)(op)     = o0;
  *(float4*)(op + 4) = o1;
}

// ---------------------------------------------------------------------------
extern "C" void kernel_launch(void* const* d_in, const int* in_sizes, int n_in,
                              void* d_out, int out_size, void* d_ws, size_t ws_size,
                              hipStream_t stream)
{
  const float* x    = (const float*)d_in[0];
  const float* sb   = (const float*)d_in[1];
  const float* Wqkv = (const float*)d_in[2];
  const float* Wout = (const float*)d_in[3];
  const float* a_in = (const float*)d_in[4];
  const float* b_in = (const float*)d_in[5];
  const float* W1   = (const float*)d_in[6];
  const float* b1   = (const float*)d_in[7];
  const float* W2   = (const float*)d_in[8];
  const float* b2   = (const float*)d_in[9];
  const float* filt = (const float*)d_in[10];

  float* outF = (float*)d_out;
  float* qkv  = outF + 196608;
  float* u    = outF + 786432;
  float* Mm   = outF + 917504;        // f32 M, out0 rows [896,1024)
  float* S    = outF + 1048576;       // partial slabs (sequentially reused)
  float* pulse = outF + 16777216;     // (B,H)   f32
  float* resp  = outF + 16777280;     // (B,H,K) f32

  // zero only the pad rows 132..191 of gemm#1's A (floats [135168,196608))
  k0_init<<<dim3(60), 256, 0, stream>>>((float4*)(outF + 135168), 15360);

  // spectral projection partials (z = 64 t-chunks), then reduce into xs+xbar
  k1_spectral_p<<<dim3(4, 4, 64), 256, 0, stream>>>(x, sb, S);
  reduce_z<<<dim3(132), 256, 0, stream>>>((const float4*)S, (float4*)outF,
                                          33792, 64, 33792);

  // qkv GEMM: 16-way split-K partials -> reduce
  gemm_aw_p<<<dim3(48, 3, 16), 256, 0, stream>>>(outF, Wqkv, S, 3072, 64, 589824);
  reduce_z<<<dim3(576), 256, 0, stream>>>((const float4*)S, (float4*)qkv,
                                          147456, 16, 147456);

  k3_small<<<dim3(64), dim3(64), 0, stream>>>(qkv, W1, b1, W2, b2,
                                              filt, a_in, b_in, u,
                                              pulse, resp);

  // out GEMM: 32-way split-K partials -> reduce into Mm
  gemm_aw_p<<<dim3(16, 2, 32), 256, 0, stream>>>(u, Wout, S, 1024, 32, 131072);
  reduce_z<<<dim3(128), 256, 0, stream>>>((const float4*)S, (float4*)Mm,
                                          32768, 32, 32768);

  // All rows except M's home, single launch, 16-row chunks
  k4_main<<<dim3(2, 1016), 256, 0, stream>>>(sb, Mm, outF);
  // M's home rows, column-partitioned across 64 blocks
  k4_tailp<<<dim3(64), 256, 0, stream>>>(sb, Mm, outF);
}

// Round 4
// 273.035 us; speedup vs baseline: 1.6980x; 1.0381x over previous
//
#include <hip/hip_runtime.h>

// B=4 T=4096 D=1024 H=16 HD=64 K=32 ; inputs f32, OUTPUTS f32.
// NO d_ws usage: all scratch lives inside the 67.1 MB f32 output-0 region.
// Zero atomics: split accumulations write disjoint per-z partial slabs,
// then reduce_z sums them.
#define B_ 4
#define T_ 4096
#define D_ 1024
#define H_ 16
#define K_ 32

// ---------------------------------------------------------------------------
// Scratch layout (f32 indices into outF; out0 = floats [0, 16777216)):
//   xs    [0      ,131072)   B*K x 1024   [reduce_zp dst]
//   xbar  [131072 ,135168)   B x 1024     [reduce_zp dst, contiguous w/ xs]
//   pad   [135168 ,196608)   zeros (rows 132..191 of gemm#1 A) [reduce_zp]
//   qkv   [196608 ,786432)   192 x 3072   [reduce_z dst]
//   u     [786432 ,917504)   128 x 1024   [pure write, k3]
//   Mm    [917504 ,1048576)  128 x 1024   [reduce_z dst] = out0 rows [896,1024)
//   S     [1048576,16777216) partial slabs, sequentially reused:
//     k1 partials  : 64 z-records of 135168 floats = 8.65M   (ends 9.70M)
//     gemm1 partials: 16 x 589824 = 9.44M  (after reduce_xs consumed k1's)
//     gemm2 partials: 32 x 131072 = 4.19M  (after reduce_qkv consumed gemm1's)
//   pulse outF[16777216 +64), resp outF[16777280 +2048)
// All S consumers finish before k4_main overwrites rows [1024,16384).
// LDS rule applied here: broadcast-read tiles are padded to 36 floats/row
// (144 B, 16B-aligned) and read as explicit float4 -> 8 ds_read_b128 per
// row instead of 32 broadcast ds_read_b32 (the round-3 LDS-issue bound).
// ---------------------------------------------------------------------------

// reduce_zp: dst[i] = sum_z src[z*stride4+i] for i<n4; dst[i]=0 for
// n4<=i<total4 (zeroes gemm#1's pad rows; replaces k0_init dispatch).
__global__ __launch_bounds__(256) void reduce_zp(
    const float4* __restrict__ src, float4* __restrict__ dst,
    const int n4, const int z, const int stride4, const int total4)
{
  int i = blockIdx.x * 256 + threadIdx.x;
  if (i >= total4) return;
  if (i >= n4){
    float4 zv; zv.x = 0.f; zv.y = 0.f; zv.z = 0.f; zv.w = 0.f;
    dst[i] = zv; return;
  }
  float s0 = 0.f, s1 = 0.f, s2 = 0.f, s3 = 0.f;
  const float4* p = src + i;
  for (int zz = 0; zz < z; ++zz){
    float4 v = p[(size_t)zz * stride4];
    s0 += v.x; s1 += v.y; s2 += v.z; s3 += v.w;
  }
  float4 o; o.x = s0; o.y = s1; o.z = s2; o.w = s3;
  dst[i] = o;
}

__global__ __launch_bounds__(256) void reduce_z(
    const float4* __restrict__ src, float4* __restrict__ dst,
    const int n4, const int z, const int stride4)
{
  int i = blockIdx.x * 256 + threadIdx.x;
  if (i >= n4) return;
  float s0 = 0.f, s1 = 0.f, s2 = 0.f, s3 = 0.f;
  const float4* p = src + i;
  for (int zz = 0; zz < z; ++zz){
    float4 v = p[(size_t)zz * stride4];
    s0 += v.x; s1 += v.y; s2 += v.z; s3 += v.w;
  }
  float4 o; o.x = s0; o.y = s1; o.z = s2; o.w = s3;
  dst[i] = o;
}

// ---------------------------------------------------------------------------
// K1 (partials): XPz[b][k][c] = sum_{t in chunk z} sb[b,t,k]*x[b,t,c]
//                XPz[xbar][b][c] = sum_{t in chunk z} x[b,t,c]
// grid (4, B, 64), block 256; ONE c per thread; t-chunk 64; 4-deep prefetch.
// sbs padded to 36/row -> aligned float4 broadcast reads (8 b128/t).
// ---------------------------------------------------------------------------
__global__ __launch_bounds__(256) void k1_spectral_p(
    const float* __restrict__ x, const float* __restrict__ sb,
    float* __restrict__ XP)
{
  const int b  = blockIdx.y;
  const int zz = blockIdx.z;
  const int t0 = zz * 64;
  const int c  = blockIdx.x * 256 + threadIdx.x;
  __shared__ __align__(16) float sbs[64][36];
  #pragma unroll
  for (int i = 0; i < 8; i++){
    int idx = threadIdx.x + i * 256;           // 2048 = 64t * 32k
    int k = idx & 31, t = idx >> 5;
    sbs[t][k] = sb[(size_t)(b * T_ + t0 + t) * K_ + k];
  }
  __syncthreads();
  float acc[32];
  #pragma unroll
  for (int k = 0; k < 32; k++) acc[k] = 0.f;
  float am = 0.f;
  const float* xp = x + (size_t)(b * T_ + t0) * D_ + c;
  float p0 = xp[0];
  float p1 = xp[D_];
  float p2 = xp[2 * D_];
  float p3 = xp[3 * D_];
  #pragma unroll 4
  for (int t = 0; t < 64; ++t){
    float xv = p0; p0 = p1; p1 = p2; p2 = p3;
    if (t < 60) p3 = xp[(size_t)(t + 4) * D_];
    am += xv;
    const float4* srow = (const float4*)&sbs[t][0];
    #pragma unroll
    for (int j = 0; j < 8; j++){
      float4 s4 = srow[j];
      acc[j * 4 + 0] = fmaf(s4.x, xv, acc[j * 4 + 0]);
      acc[j * 4 + 1] = fmaf(s4.y, xv, acc[j * 4 + 1]);
      acc[j * 4 + 2] = fmaf(s4.z, xv, acc[j * 4 + 2]);
      acc[j * 4 + 3] = fmaf(s4.w, xv, acc[j * 4 + 3]);
    }
  }
  float* o = XP + (size_t)zz * 135168 + (size_t)(b * K_) * D_ + c;
  #pragma unroll
  for (int k = 0; k < 32; k++) o[(size_t)k * D_] = acc[k];
  XP[(size_t)zz * 135168 + 131072 + b * D_ + c] = am;
}

// ---------------------------------------------------------------------------
// gemm_aw_p: Cp[z][m][n] = sum_{c in split} A[m][c]*W[n][c]; PURE STORES.
// grid (N/64, M/64, csplit), block 256; 64x64 tile; c-chunk 32 (17.4 KB LDS).
// Register-staged double buffer. LDS reads are aligned b128 (68-row stride).
// ---------------------------------------------------------------------------
__global__ __launch_bounds__(256) void gemm_aw_p(
    const float* __restrict__ A, const float* __restrict__ W,
    float* __restrict__ Cp, const int N, const int cPerSplit, const int MN)
{
  __shared__ __align__(16) float As[32][68];
  __shared__ __align__(16) float Ws[32][68];
  const int nt = blockIdx.x, mt = blockIdx.y;
  const int cbase = blockIdx.z * cPerSplit;
  const int tx = threadIdx.x & 15, ty = threadIdx.x >> 4;
  const int sc = threadIdx.x & 31, sr = threadIdx.x >> 5;  // staging coords
  float acc[4][4];
  #pragma unroll
  for (int i = 0; i < 4; i++)
    #pragma unroll
    for (int j = 0; j < 4; j++) acc[i][j] = 0.f;

  float ra[8], rw[8];
  const float* Ap = A + (size_t)(mt * 64 + sr) * 1024 + cbase + sc;
  const float* Wp = W + (size_t)(nt * 64 + sr) * 1024 + cbase + sc;
  #pragma unroll
  for (int i = 0; i < 8; i++){ ra[i] = Ap[(size_t)(i * 8) * 1024];
                               rw[i] = Wp[(size_t)(i * 8) * 1024]; }
  #pragma unroll
  for (int i = 0; i < 8; i++){ As[sc][sr + i * 8] = ra[i];
                               Ws[sc][sr + i * 8] = rw[i]; }
  __syncthreads();

  for (int cc = 32; cc < cPerSplit; cc += 32){
    #pragma unroll
    for (int i = 0; i < 8; i++){ ra[i] = Ap[(size_t)(i * 8) * 1024 + cc];
                                 rw[i] = Wp[(size_t)(i * 8) * 1024 + cc]; }
    #pragma unroll 4
    for (int c = 0; c < 32; ++c){
      const float4 a4 = *(const float4*)&As[c][ty * 4];
      const float4 w4 = *(const float4*)&Ws[c][tx * 4];
      acc[0][0] = fmaf(a4.x, w4.x, acc[0][0]);
      acc[0][1] = fmaf(a4.x, w4.y, acc[0][1]);
      acc[0][2] = fmaf(a4.x, w4.z, acc[0][2]);
      acc[0][3] = fmaf(a4.x, w4.w, acc[0][3]);
      acc[1][0] = fmaf(a4.y, w4.x, acc[1][0]);
      acc[1][1] = fmaf(a4.y, w4.y, acc[1][1]);
      acc[1][2] = fmaf(a4.y, w4.z, acc[1][2]);
      acc[1][3] = fmaf(a4.y, w4.w, acc[1][3]);
      acc[2][0] = fmaf(a4.z, w4.x, acc[2][0]);
      acc[2][1] = fmaf(a4.z, w4.y, acc[2][1]);
      acc[2][2] = fmaf(a4.z, w4.z, acc[2][2]);
      acc[2][3] = fmaf(a4.z, w4.w, acc[2][3]);
      acc[3][0] = fmaf(a4.w, w4.x, acc[3][0]);
      acc[3][1] = fmaf(a4.w, w4.y, acc[3][1]);
      acc[3][2] = fmaf(a4.w, w4.z, acc[3][2]);
      acc[3][3] = fmaf(a4.w, w4.w, acc[3][3]);
    }
    __syncthreads();
    #pragma unroll
    for (int i = 0; i < 8; i++){ As[sc][sr + i * 8] = ra[i];
                                 Ws[sc][sr + i * 8] = rw[i]; }
    __syncthreads();
  }
  #pragma unroll 4
  for (int c = 0; c < 32; ++c){
    const float4 a4 = *(const float4*)&As[c][ty * 4];
    const float4 w4 = *(const float4*)&Ws[c][tx * 4];
    acc[0][0] = fmaf(a4.x, w4.x, acc[0][0]);
    acc[0][1] = fmaf(a4.x, w4.y, acc[0][1]);
    acc[0][2] = fmaf(a4.x, w4.z, acc[0][2]);
    acc[0][3] = fmaf(a4.x, w4.w, acc[0][3]);
    acc[1][0] = fmaf(a4.y, w4.x, acc[1][0]);
    acc[1][1] = fmaf(a4.y, w4.y, acc[1][1]);
    acc[1][2] = fmaf(a4.y, w4.z, acc[1][2]);
    acc[1][3] = fmaf(a4.y, w4.w, acc[1][3]);
    acc[2][0] = fmaf(a4.z, w4.x, acc[2][0]);
    acc[2][1] = fmaf(a4.z, w4.y, acc[2][1]);
    acc[2][2] = fmaf(a4.z, w4.z, acc[2][2]);
    acc[2][3] = fmaf(a4.z, w4.w, acc[2][3]);
    acc[3][0] = fmaf(a4.w, w4.x, acc[3][0]);
    acc[3][1] = fmaf(a4.w, w4.y, acc[3][1]);
    acc[3][2] = fmaf(a4.w, w4.z, acc[3][2]);
    acc[3][3] = fmaf(a4.w, w4.w, acc[3][3]);
  }
  float* cp = Cp + (size_t)blockIdx.z * MN;
  #pragma unroll
  for (int i = 0; i < 4; i++){
    float4 o; o.x = acc[i][0]; o.y = acc[i][1]; o.z = acc[i][2]; o.w = acc[i][3];
    *(float4*)(cp + (size_t)(mt * 64 + ty * 4 + i) * N + nt * 64 + tx * 4) = o;
  }
}

// ---------------------------------------------------------------------------
// K3: pulse (qkv row 128+b = xbar@Wqkv.T), attn_spec, soliton ODE, u=resp*v_spec
// grid 64 blocks (b*16+h), 64 threads. All outputs f32.
// ---------------------------------------------------------------------------
__global__ __launch_bounds__(64) void k3_small(
    const float* __restrict__ qkvC,
    const float* __restrict__ W1, const float* __restrict__ b1,
    const float* __restrict__ W2, const float* __restrict__ b2,
    const float* __restrict__ filt,
    const float* __restrict__ a_in, const float* __restrict__ b_in,
    float* __restrict__ u, float* __restrict__ out_pulse,
    float* __restrict__ out_resp)
{
  const int b = blockIdx.x >> 4, h = blockIdx.x & 15;
  const int d = threadIdx.x;
  __shared__ float qm[64];
  __shared__ float h1s[32];
  __shared__ float rsp[32];
  qm[d] = qkvC[(size_t)(128 + b) * 3072 + h * 64 + d] * (1.0f / 4096.0f);
  __syncthreads();
  if (d < 32){
    float z = b1[d];
    for (int j = 0; j < 64; j++) z = fmaf(qm[j], W1[d * 64 + j], z);
    h1s[d] = z / (1.0f + __expf(-z));             // silu
  }
  __syncthreads();
  if (d == 0){
    float z2 = b2[0];
    for (int j = 0; j < 32; j++) z2 = fmaf(h1s[j], W2[j], z2);
    out_pulse[b * H_ + h] = 4.0f + log1pf(__expf(z2));  // PULSE_BASE+softplus
  }
  if (d < 32){
    const int k = d;
    const float* qrow = qkvC + (size_t)(b * K_ + k) * 3072 + h * 64;
    const float* krow = qrow + 1024;
    float s = 0.f;
    for (int j = 0; j < 64; j++) s = fmaf(qrow[j], krow[j], s);
    float fg = 1.0f / (1.0f + __expf(-filt[h * 32 + k]));
    s = s * 0.125f * fg;                          // /sqrt(64)*sigmoid(filter)
    float av = a_in[0], bv = b_in[0];
    float sc = fmaxf(fabsf(s), 1e-6f);
    float sn = s / sc;
    float I  = (fabsf(s) > 0.5f) ? sn : 0.1f * sn;
    float v = 0.f, w = 0.f;
    #pragma unroll
    for (int it = 0; it < 5; ++it){
      float dv = v - v * v * v * (1.0f / 3.0f) - w + I;
      float dw = (v + av - bv * w) * 10.0f;       // /TAU
      v = fminf(fmaxf(v + 0.2f * dv, -3.0f), 3.0f);
      w = fminf(fmaxf(w + 0.2f * dw, -3.0f), 3.0f);
    }
    float r = v * sc;
    rsp[k] = r;
    out_resp[(b * H_ + h) * K_ + k] = r;
  }
  __syncthreads();
  for (int k = 0; k < 32; k++){
    u[(size_t)(b * K_ + k) * D_ + h * 64 + d] =
        rsp[k] * qkvC[(size_t)(b * K_ + k) * 3072 + 2048 + h * 64 + d];
  }
}

// ---------------------------------------------------------------------------
// k4_main: all out0 rows EXCEPT [896,1024); 16-row chunks.
// grid (2, 1016), block 256; thread owns 2 consecutive e.
// sbs padded to 36/row -> aligned float4 broadcast reads (8 b128/t).
// ---------------------------------------------------------------------------
__global__ __launch_bounds__(256) void k4_main(
    const float* __restrict__ sb, const float* __restrict__ Mf,
    float* __restrict__ out)
{
  const int yy = blockIdx.y;
  const int r0 = (yy < 56 ? yy : yy + 8) * 16;   // skip M home rows [896,1024)
  const int b  = r0 >> 12;
  const int e0 = blockIdx.x * 512 + threadIdx.x * 2;
  __shared__ __align__(16) float sbs[16][36];
  #pragma unroll
  for (int i = 0; i < 2; i++){
    int idx = threadIdx.x + i * 256;           // 512 = 16t * 32k
    int k = idx & 31, t = idx >> 5;
    sbs[t][k] = sb[(size_t)(r0 + t) * K_ + k];
  }
  __syncthreads();
  float mx[32], my[32];
  const float* mp = Mf + (size_t)b * K_ * D_ + e0;
  #pragma unroll
  for (int k = 0; k < 32; k++){ mx[k] = mp[(size_t)k * D_]; my[k] = mp[(size_t)k * D_ + 1]; }
  float* op = out + (size_t)r0 * D_ + e0;
  for (int t = 0; t < 16; ++t){
    float ox = 0.f, oy = 0.f;
    const float4* srow = (const float4*)&sbs[t][0];
    #pragma unroll
    for (int j = 0; j < 8; j++){
      float4 s4 = srow[j];
      ox = fmaf(s4.x, mx[j * 4 + 0], ox); oy = fmaf(s4.x, my[j * 4 + 0], oy);
      ox = fmaf(s4.y, mx[j * 4 + 1], ox); oy = fmaf(s4.y, my[j * 4 + 1], oy);
      ox = fmaf(s4.z, mx[j * 4 + 2], ox); oy = fmaf(s4.z, my[j * 4 + 2], oy);
      ox = fmaf(s4.w, mx[j * 4 + 3], ox); oy = fmaf(s4.w, my[j * 4 + 3], oy);
    }
    float2 o2; o2.x = ox; o2.y = oy;
    *(float2*)(op + (size_t)t * D_) = o2;
  }
}

// ---------------------------------------------------------------------------
// k4_tailp: out0 rows [896,1024) — M's home — COLUMN-PARTITIONED.
// grid (64), block 256. Block j owns columns [j*16, j*16+16); race-free.
// (sbs[128][33] kept: lanes span 32 distinct t-rows -> 2-way banking, free.)
// ---------------------------------------------------------------------------
__global__ __launch_bounds__(256) void k4_tailp(
    const float* __restrict__ sb, const float* __restrict__ Mf,
    float* __restrict__ out)
{
  __shared__ float sbs[128][33];               // 16.9 KB
  __shared__ __align__(16) float Ms[32][16];   // 2 KB: this block's M columns
  const int j = blockIdx.x;
  #pragma unroll
  for (int i = 0; i < 2; i++){
    int idx = threadIdx.x + i * 256;           // 512 = 32k * 16e
    int k = idx >> 4, e = idx & 15;
    Ms[k][e] = Mf[(size_t)k * D_ + j * 16 + e];
  }
  #pragma unroll
  for (int i = 0; i < 16; i++){
    int idx = threadIdx.x + i * 256;           // 4096 = 128t * 32k
    int k = idx & 31, t = idx >> 5;
    sbs[t][k] = sb[(size_t)(896 + t) * K_ + k];
  }
  __syncthreads();
  const int t  = threadIdx.x >> 1;
  const int c0 = (threadIdx.x & 1) * 8;
  float a0 = 0.f, a1 = 0.f, a2 = 0.f, a3 = 0.f;
  float a4 = 0.f, a5 = 0.f, a6 = 0.f, a7 = 0.f;
  #pragma unroll
  for (int k = 0; k < 32; k++){
    float s = sbs[t][k];
    const float4 m0 = *(const float4*)&Ms[k][c0];
    const float4 m1 = *(const float4*)&Ms[k][c0 + 4];
    a0 = fmaf(s, m0.x, a0); a1 = fmaf(s, m0.y, a1);
    a2 = fmaf(s, m0.z, a2); a3 = fmaf(s, m0.w, a3);
    a4 = fmaf(s, m1.x, a4); a5 = fmaf(s, m1.y, a5);
    a6 = fmaf(s, m1.z, a6); a7 = fmaf(s, m1.w, a7);
  }
  float* op = out + (size_t)(896 + t) * D_ + j * 16 + c0;
  float4 o0; o0.x = a0; o0.y = a1; o0.z = a2; o0.w = a3;
  float4 o1; o1.x = a4; o1.y = a5; o1.z = a6; o1.w = a7;
  *(float4*)(op)     = o0;
  *(float4*)(op + 4) = o1;
}

// ---------------------------------------------------------------------------
extern "C" void kernel_launch(void* const* d_in, const int* in_sizes, int n_in,
                              void* d_out, int out_size, void* d_ws, size_t ws_size,
                              hipStream_t stream)
{
  const float* x    = (const float*)d_in[0];
  const float* sb   = (const float*)d_in[1];
  const float* Wqkv = (const float*)d_in[2];
  const float* Wout = (const float*)d_in[3];
  const float* a_in = (const float*)d_in[4];
  const float* b_in = (const float*)d_in[5];
  const float* W1   = (const float*)d_in[6];
  const float* b1   = (const float*)d_in[7];
  const float* W2   = (const float*)d_in[8];
  const float* b2   = (const float*)d_in[9];
  const float* filt = (const float*)d_in[10];

  float* outF = (float*)d_out;
  float* qkv  = outF + 196608;
  float* u    = outF + 786432;
  float* Mm   = outF + 917504;        // f32 M, out0 rows [896,1024)
  float* S    = outF + 1048576;       // partial slabs (sequentially reused)
  float* pulse = outF + 16777216;     // (B,H)   f32
  float* resp  = outF + 16777280;     // (B,H,K) f32

  // spectral projection partials (z = 64 t-chunks)
  k1_spectral_p<<<dim3(4, 4, 64), 256, 0, stream>>>(x, sb, S);
  // reduce into xs+xbar AND zero gemm#1's pad rows (fused k0_init)
  reduce_zp<<<dim3(192), 256, 0, stream>>>((const float4*)S, (float4*)outF,
                                           33792, 64, 33792, 49152);

  // qkv GEMM: 16-way split-K partials -> reduce
  gemm_aw_p<<<dim3(48, 3, 16), 256, 0, stream>>>(outF, Wqkv, S, 3072, 64, 589824);
  reduce_z<<<dim3(576), 256, 0, stream>>>((const float4*)S, (float4*)qkv,
                                          147456, 16, 147456);

  k3_small<<<dim3(64), dim3(64), 0, stream>>>(qkv, W1, b1, W2, b2,
                                              filt, a_in, b_in, u,
                                              pulse, resp);

  // out GEMM: 32-way split-K partials -> reduce into Mm
  gemm_aw_p<<<dim3(16, 2, 32), 256, 0, stream>>>(u, Wout, S, 1024, 32, 131072);
  reduce_z<<<dim3(128), 256, 0, stream>>>((const float4*)S, (float4*)Mm,
                                          32768, 32, 32768);

  // All rows except M's home, single launch, 16-row chunks
  k4_main<<<dim3(2, 1016), 256, 0, stream>>>(sb, Mm, outF);
  // M's home rows, column-partitioned across 64 blocks
  k4_tailp<<<dim3(64), 256, 0, stream>>>(sb, Mm, outF);
}